// Round 9
// baseline (517.994 us; speedup 1.0000x reference)
//
#include <hip/hip_runtime.h>

typedef __bf16 bf16_t;
typedef __bf16 bf16x8 __attribute__((ext_vector_type(8)));
typedef __bf16 bf16x4 __attribute__((ext_vector_type(4)));
typedef float  f32x4  __attribute__((ext_vector_type(4)));
typedef short  s16x4  __attribute__((ext_vector_type(4)));

#define DEV __device__ __forceinline__

// ---- constants ----
#define BB 8
#define SS 2048
#define HH 768
#define NHH 12
#define HD 64
#define NX (BB*SS*HH)      // 12582912
#define NW (HH*HH)         // 589824

// async global->LDS, 16B per lane; LDS dest must be wave-uniform base + lane*16
DEV void gl_lds16(const void* g, void* s) {
  __builtin_amdgcn_global_load_lds(
      (__attribute__((address_space(1))) void*)(void*)g,
      (__attribute__((address_space(3))) void*)s, 16, 0, 0);
}

DEV int swz4(int r) { return (r ^ (r >> 2)) & 3; }   // 4-chunk (64B) rows

DEV f32x4 mfma32(bf16x8 a, bf16x8 b, f32x4 c) {
  return __builtin_amdgcn_mfma_f32_16x16x32_bf16(a, b, c, 0, 0, 0);
}

// ============ kernel 1: fp32 -> bf16 conversion (X, Wq, Wk, Wv) ============
__global__ __launch_bounds__(256) void cvt_kernel(
    const float* __restrict__ X, const float* __restrict__ Wq,
    const float* __restrict__ Wk, const float* __restrict__ Wv,
    bf16_t* __restrict__ Xb, bf16_t* __restrict__ Wb) {
  int idx = (blockIdx.x * 256 + threadIdx.x) * 4;
  const float* src;
  bf16_t* dst;
  if (idx < NX) { src = X + idx; dst = Xb + idx; }
  else {
    int j = idx - NX;
    int w = j / NW;
    int jj = j - w * NW;
    src = (w == 0 ? Wq : (w == 1 ? Wk : Wv)) + jj;
    dst = Wb + j;
  }
  float4 v = *(const float4*)src;
  bf16x4 o;
  o[0] = (bf16_t)v.x; o[1] = (bf16_t)v.y; o[2] = (bf16_t)v.z; o[3] = (bf16_t)v.w;
  *(bf16x4*)dst = o;
}

// ============ kernel 2: fused QKV projection GEMM ============
// z=0 -> Q [b][h][s][d] PRE-SCALED by 0.125*log2(e), z=1 -> K
// z=2 -> V^T [b][h][d][s] with a PERMUTED kv order inside every 64-block:
//   stored = (i>>1)*32 + lq*8 + (i&1)*4 + r   for original sb = i*16+lq*4+r.
//
// Round-9: operand-SWAPPED MFMA for z<2.  The old Q/K epilogue issued 64
// scalar 2-byte stores per thread (25M scalar VMEM stores total + address
// VALU) -- the dominant qkv cost (qkv ~130us vs 7us MFMA floor).  Swapping
// mfma(W-frag, X-frag) transposes C so reg r runs along d (contiguous in
// Q/K): 16x 8B bf16x4 stores per thread, f32x4 bias loads, h uniform/wave.
// z==2 keeps the old orientation (r along s, which V^T layout needs).
// XCD-chunked swizzle (round-8) kept: swz = (id&7)*288 + id>>3.
__global__ __launch_bounds__(256) void qkv_gemm(
    const bf16_t* __restrict__ Xb, const bf16_t* __restrict__ Wb,
    const float* __restrict__ bq, const float* __restrict__ bk,
    const float* __restrict__ bv,
    bf16_t* __restrict__ Q, bf16_t* __restrict__ K, bf16_t* __restrict__ VT) {
  __shared__ alignas(16) bf16_t ldsA[2][128 * 32];
  __shared__ alignas(16) bf16_t ldsB[2][128 * 32];

  const int t = threadIdx.x;
  const int w = t >> 6, l = t & 63, lr = l & 15, lq = l >> 4;
  const int wr = w >> 1, wc = w & 1;

  const int id = blockIdx.x;
  const int swz = (id & 7) * 288 + (id >> 3);       // XCD-chunked remap
  const int z = swz / 768;
  const int rem = swz - z * 768;
  const int m0 = (rem / 6) * 128, n0 = (rem % 6) * 128;

  const bf16_t* W = Wb + z * NW;
  const float* bias = (z == 0) ? bq : (z == 1) ? bk : bv;
  // Q carries the softmax scale 0.125 and the exp2 conversion log2(e):
  const float osc = (z == 0) ? 0.1803368801f : 1.0f;

  const int sl0 = t, sl1 = t + 256;
  const int ra0 = sl0 >> 2, qa0 = (sl0 & 3) ^ swz4(ra0);
  const int ra1 = sl1 >> 2, qa1 = (sl1 & 3) ^ swz4(ra1);
  const bf16_t* A0 = Xb + (m0 + ra0) * HH + qa0 * 8;
  const bf16_t* A1 = Xb + (m0 + ra1) * HH + qa1 * 8;
  const bf16_t* B0 = W + (n0 + ra0) * HH + qa0 * 8;
  const bf16_t* B1 = W + (n0 + ra1) * HH + qa1 * 8;

  f32x4 acc[4][4] = {};

  // offA: X-panel fragment offsets (m rows, wr); offB: W-panel (n rows, wc)
  int offA[4], offB[4];
#pragma unroll
  for (int i = 0; i < 4; ++i) {
    int Ra = wr * 64 + i * 16 + lr;
    offA[i] = (Ra * 4 + (lq ^ swz4(Ra))) * 8;
    int Rb = wc * 64 + i * 16 + lr;
    offB[i] = (Rb * 4 + (lq ^ swz4(Rb))) * 8;
  }

  // Operand selection: mfma(op0, op1): D row(lq,r) <- op0 rows, col(lr) <- op1.
  // z==2: op0 = X (row=m), op1 = W (col=n)  [V^T epilogue needs r along s=m]
  // z<2 : op0 = W (row=n), op1 = X (col=m)  [Q/K epilogue: r along d=n]
  const bool zv = (z == 2);
  const bf16_t* LI = zv ? &ldsA[0][0] : &ldsB[0][0];
  const bf16_t* LJ = zv ? &ldsB[0][0] : &ldsA[0][0];
  int offI[4], offJ[4];
#pragma unroll
  for (int i = 0; i < 4; ++i) {
    offI[i] = zv ? offA[i] : offB[i];
    offJ[i] = zv ? offB[i] : offA[i];
  }

  auto stage = [&](int buf, int kt) {
    int ko = kt * 32;
    gl_lds16(A0 + ko, ldsA[buf] + sl0 * 8);
    gl_lds16(A1 + ko, ldsA[buf] + sl1 * 8);
    gl_lds16(B0 + ko, ldsB[buf] + sl0 * 8);
    gl_lds16(B1 + ko, ldsB[buf] + sl1 * 8);
  };

  auto compute = [&](const int buf) {
    bf16x8 fa[4], fb[4];
#pragma unroll
    for (int i = 0; i < 4; ++i) fa[i] = *(const bf16x8*)(LI + buf * 4096 + offI[i]);
#pragma unroll
    for (int j = 0; j < 4; ++j) fb[j] = *(const bf16x8*)(LJ + buf * 4096 + offJ[j]);
#pragma unroll
    for (int i = 0; i < 4; ++i)
#pragma unroll
      for (int j = 0; j < 4; ++j)
        acc[i][j] = __builtin_amdgcn_mfma_f32_16x16x32_bf16(fa[i], fb[j], acc[i][j], 0, 0, 0);
  };

  stage(0, 0);
  __syncthreads();     // tile0 drained
  stage(1, 1);         // in flight under compute(0)
  compute(0);
  for (int kt = 1; kt < 23; kt += 2) {
    __syncthreads();   // drains stage(buf1,kt); all waves done with buf0
    stage(0, kt + 1);
    compute(1);
    __syncthreads();   // drains stage(buf0,kt+1); all waves done with buf1
    stage(1, kt + 2);
    compute(0);
  }
  __syncthreads();     // drains stage(buf1,23)
  compute(1);

  const int mb = m0 + wr * 64, nb = n0 + wc * 64;
  if (zv) {
    // ---- V^T epilogue (row=m via lq,r; col=n via lr) -- unchanged ----
#pragma unroll
    for (int j = 0; j < 4; ++j) {
      int n = nb + j * 16 + lr;
      int h = n >> 6, d = n & 63;
      float bbias = bias[n];
#pragma unroll
      for (int i = 0; i < 4; ++i) {
        int mrow = mb + i * 16 + lq * 4;
        int b = mrow >> 11, s = mrow & 2047;
        bf16x4 pk;
#pragma unroll
        for (int r = 0; r < 4; ++r) pk[r] = (bf16_t)(acc[i][j][r] + bbias);
        // permuted kv order within the 64-block (see header comment)
        int sperm = (s & ~63) + ((i >> 1) << 5) + (lq << 3) + ((i & 1) << 2);
        *(bf16x4*)(VT + ((size_t)(b * NHH + h) * HD + d) * SS + sperm) = pk;
      }
    }
  } else {
    // ---- Q/K epilogue (row=n via lq,r; col=m via lr): vector stores ----
    bf16_t* O = (z == 0) ? Q : K;
    const int h = nb >> 6;                 // uniform per wave (nb mult of 64)
#pragma unroll
    for (int j = 0; j < 4; ++j) {          // j indexes m-subblocks (op1)
      int mrow = mb + j * 16 + lr;
      int b = mrow >> 11, s = mrow & 2047;
      bf16_t* orow = O + ((size_t)(b * NHH + h) * SS + s) * HD;
#pragma unroll
      for (int i = 0; i < 4; ++i) {        // i indexes n-subblocks (op0)
        int dq = i * 16 + lq * 4;          // d quad within head
        f32x4 bi = *(const f32x4*)(bias + nb + dq);
        bf16x4 pk;
#pragma unroll
        for (int r = 0; r < 4; ++r) pk[r] = (bf16_t)((acc[i][j][r] + bi[r]) * osc);
        *(bf16x4*)(orow + dq) = pk;
      }
    }
  }
}

// ============ kernel 3: flash attention (all-x32 MFMA, zero-cost P re-layout) ============
// Round-7 verified: x32-only MFMA + permuted-V register-concat P, bank
// conflicts = 0, FETCH = ideal 69 MB, both pipes ~36%.
// Round-9: launch_bounds(256,5) -> 5 blocks/CU (LDS 32KB x 5 = 160KB exact;
// VGPR 64 <= 102 cap for 5 waves/EU, so no spill -- unlike round-1 where the
// kernel needed more than the cap).  Occupancy 35% -> ~45%.
__global__ __launch_bounds__(256, 5) void flash_kernel(
    const bf16_t* __restrict__ Q, const bf16_t* __restrict__ K,
    const bf16_t* __restrict__ VT, const float* __restrict__ mask,
    float* __restrict__ out) {
  // [buf][0] = K tile (64x64), [buf][1] = V^T tile (64x64).  32768 B total.
  __shared__ alignas(16) bf16_t ldsKV[2][2][64 * 64];

  const int t = threadIdx.x;
  const int w = t >> 6, l = t & 63, lr = l & 15, lq = l >> 4;
  const int rs7 = lr & 7;
  const int bh = blockIdx.x % 96, b = bh / NHH, h = bh - b * NHH;
  const int s0 = (blockIdx.x / 96) * 128;
  const bf16_t* Qb = Q + ((size_t)bh * SS + s0) * HD;
  const bf16_t* Kb = K + (size_t)bh * SS * HD;
  const bf16_t* Vb = VT + (size_t)bh * HD * SS;
  const float* mb = mask + b * SS;

  // ---- stage Q (128x64 = 16 KB) into the buf0 region, 8-chunk xor swizzle ----
  bf16_t* qs = &ldsKV[0][0][0];
#pragma unroll
  for (int i = 0; i < 4; ++i) {
    int sl = t + i * 256;
    int r = sl >> 3, q = (sl & 7) ^ (r & 7);
    gl_lds16(Qb + r * HD + q * 8, qs + sl * 8);
  }
  __syncthreads();   // Q staged

  bf16x8 aq0[2], aq1[2];
#pragma unroll
  for (int qi = 0; qi < 2; ++qi) {
    int Rq = w * 32 + qi * 16 + lr;
    aq0[qi] = *(const bf16x8*)(qs + (Rq * 8 + (lq ^ (Rq & 7))) * 8);
    aq1[qi] = *(const bf16x8*)(qs + (Rq * 8 + ((lq + 4) ^ (Rq & 7))) * 8);
  }
  __syncthreads();   // all waves hold Q in registers; buf0 region reusable

  const int c0 = t, c1 = t + 256;
  const int cr0 = c0 >> 3, cq0 = (c0 & 7) ^ (cr0 & 7);
  const int cr1 = c1 >> 3, cq1 = (c1 & 7) ^ (cr1 & 7);

  auto stage = [&](int buf, int kt) {
    const bf16_t* ks = Kb + kt * 64 * HD;
    gl_lds16(ks + cr0 * HD + cq0 * 8, ldsKV[buf][0] + c0 * 8);
    gl_lds16(ks + cr1 * HD + cq1 * 8, ldsKV[buf][0] + c1 * 8);
    gl_lds16(Vb + cr0 * SS + kt * 64 + cq0 * 8, ldsKV[buf][1] + c0 * 8);
    gl_lds16(Vb + cr1 * SS + kt * 64 + cq1 * 8, ldsKV[buf][1] + c1 * 8);
  };

  // ---- per-lane LDS byte bases (loop-invariant; reads = base + imm) ----
  // K: row Rk = j*16+lr, chunk lq / lq+4 (xor rs7), + j*2048
  const char* LB = (const char*)&ldsKV[0][0][0];
  const int kb0 = lr * 128 + ((lq ^ rs7) * 16);
  const int kb1 = lr * 128 + (((lq + 4) ^ rs7) * 16);
  // V (x32 A-frag): row d = dt*16+lr, stored-octet chunk gi*4+lq (xor rs7)
  int vg[2];
#pragma unroll
  for (int g = 0; g < 2; ++g) vg[g] = lr * 128 + (((g * 4 + lq) ^ rs7) * 16);

  f32x4 O[2][4] = {};
  f32x4 Lacc[2] = {};
  bf16x8 ones8;
#pragma unroll
  for (int r = 0; r < 8; ++r) ones8[r] = (bf16_t)1.0f;

  const float L2E = 1.44269504f;

  // BUFB: byte offset of the double-buffer half (0 or 16384) — literal at call sites.
  auto compute = [&](const int BUFB, int kt) {
    const char* Kbase = LB + BUFB;
    const char* Vbase = LB + BUFB + 8192;

#pragma unroll
    for (int gi = 0; gi < 2; ++gi) {
      bf16x8 pf[2];   // per qi: x32 B-frag octet = concat of quads j=2gi, 2gi+1
#pragma unroll
      for (int jj = 0; jj < 2; ++jj) {
        const int j = gi * 2 + jj;
        bf16x8 k0 = *(const bf16x8*)(Kbase + kb0 + j * 2048);
        bf16x8 k1 = *(const bf16x8*)(Kbase + kb1 + j * 2048);
        f32x4 mvv = *(const f32x4*)(mb + kt * 64 + j * 16 + lq * 4);
        f32x4 marg = mvv * L2E;
#pragma unroll
        for (int qi = 0; qi < 2; ++qi) {
          f32x4 st = mfma32(k0, aq0[qi], marg);
          st = mfma32(k1, aq1[qi], st);
#pragma unroll
          for (int r = 0; r < 4; ++r)
            pf[qi][jj * 4 + r] = (bf16_t)__builtin_amdgcn_exp2f(st[r]);
        }
      }
      // ---- l += 1^T . P^T  (K=32, MFMA pipe) ----
      Lacc[0] = mfma32(ones8, pf[0], Lacc[0]);
      Lacc[1] = mfma32(ones8, pf[1], Lacc[1]);
      // ---- O^T += V^T . P^T  (K=32, V in permuted-stored order) ----
#pragma unroll
      for (int dt = 0; dt < 4; ++dt) {
        bf16x8 av = *(const bf16x8*)(Vbase + vg[gi] + dt * 2048);
        O[0][dt] = mfma32(av, pf[0], O[0][dt]);
        O[1][dt] = mfma32(av, pf[1], O[1][dt]);
      }
    }
  };

  stage(0, 0);
  __syncthreads();   // tile0 drained
  stage(1, 1);       // in flight under compute(0)
  compute(0, 0);
  for (int kt = 1; kt < 31; kt += 2) {
    __syncthreads();               // drains stage of buf1(kt); all waves done with buf0
    stage(0, kt + 1);
    compute(16384, kt);
    __syncthreads();               // drains stage of buf0(kt+1); all done with buf1
    stage(1, kt + 2);
    compute(0, kt + 1);
  }
  __syncthreads();
  compute(16384, 31);

  // ---- epilogue: inv from MFMA row-sum (no shuffles) ----
#pragma unroll
  for (int qi = 0; qi < 2; ++qi) {
    float inv = 1.0f / Lacc[qi][0];
    int srow = s0 + w * 32 + qi * 16 + lr;
    float* op = out + ((size_t)b * SS + srow) * HH + h * HD;
#pragma unroll
    for (int dt = 0; dt < 4; ++dt) {
      f32x4 o = O[qi][dt];
      o *= inv;
      *(f32x4*)(op + dt * 16 + lq * 4) = o;
    }
  }
}

// ============ launcher ============
extern "C" void kernel_launch(void* const* d_in, const int* in_sizes, int n_in,
                              void* d_out, int out_size, void* d_ws, size_t ws_size,
                              hipStream_t stream) {
  const float* X    = (const float*)d_in[0];
  const float* mask = (const float*)d_in[1];
  const float* Wq   = (const float*)d_in[2];
  const float* bq   = (const float*)d_in[3];
  const float* Wk   = (const float*)d_in[4];
  const float* bk   = (const float*)d_in[5];
  const float* Wv   = (const float*)d_in[6];
  const float* bv   = (const float*)d_in[7];
  float* out = (float*)d_out;

  char* ws = (char*)d_ws;
  bf16_t* Xb = (bf16_t*)(ws);                        // 25165824 B
  bf16_t* Wb = (bf16_t*)(ws + 25165824);             //  3538944 B
  bf16_t* Qb = (bf16_t*)(ws + 28704768);             // 25165824 B
  bf16_t* Kb = (bf16_t*)(ws + 53870592);             // 25165824 B
  bf16_t* VT = (bf16_t*)(ws + 79036416);             // 25165824 B

  cvt_kernel<<<14016, 256, 0, stream>>>(X, Wq, Wk, Wv, Xb, Wb);
  qkv_gemm<<<2304, 256, 0, stream>>>(Xb, Wb, bq, bk, bv, Qb, Kb, VT);
  flash_kernel<<<1536, 256, 0, stream>>>(Qb, Kb, VT, mask, out);
}

// Round 10
// 326.593 us; speedup vs baseline: 1.5861x; 1.5861x over previous
//
#include <hip/hip_runtime.h>

typedef __bf16 bf16_t;
typedef __bf16 bf16x8 __attribute__((ext_vector_type(8)));
typedef __bf16 bf16x4 __attribute__((ext_vector_type(4)));
typedef float  f32x4  __attribute__((ext_vector_type(4)));
typedef short  s16x4  __attribute__((ext_vector_type(4)));

#define DEV __device__ __forceinline__

// ---- constants ----
#define BB 8
#define SS 2048
#define HH 768
#define NHH 12
#define HD 64
#define NX (BB*SS*HH)      // 12582912
#define NW (HH*HH)         // 589824

// async global->LDS, 16B per lane; LDS dest must be wave-uniform base + lane*16
DEV void gl_lds16(const void* g, void* s) {
  __builtin_amdgcn_global_load_lds(
      (__attribute__((address_space(1))) void*)(void*)g,
      (__attribute__((address_space(3))) void*)s, 16, 0, 0);
}

DEV int swz4(int r) { return (r ^ (r >> 2)) & 3; }   // 4-chunk (64B) rows

DEV f32x4 mfma32(bf16x8 a, bf16x8 b, f32x4 c) {
  return __builtin_amdgcn_mfma_f32_16x16x32_bf16(a, b, c, 0, 0, 0);
}

// ============ kernel 1: fp32 -> bf16 conversion (X, Wq, Wk, Wv) ============
__global__ __launch_bounds__(256) void cvt_kernel(
    const float* __restrict__ X, const float* __restrict__ Wq,
    const float* __restrict__ Wk, const float* __restrict__ Wv,
    bf16_t* __restrict__ Xb, bf16_t* __restrict__ Wb) {
  int idx = (blockIdx.x * 256 + threadIdx.x) * 4;
  const float* src;
  bf16_t* dst;
  if (idx < NX) { src = X + idx; dst = Xb + idx; }
  else {
    int j = idx - NX;
    int w = j / NW;
    int jj = j - w * NW;
    src = (w == 0 ? Wq : (w == 1 ? Wk : Wv)) + jj;
    dst = Wb + j;
  }
  float4 v = *(const float4*)src;
  bf16x4 o;
  o[0] = (bf16_t)v.x; o[1] = (bf16_t)v.y; o[2] = (bf16_t)v.z; o[3] = (bf16_t)v.w;
  *(bf16x4*)dst = o;
}

// ============ kernel 2: fused QKV projection GEMM ============
// z=0 -> Q [b][h][s][d] PRE-SCALED by 0.125*log2(e), z=1 -> K
// z=2 -> V^T [b][h][d][s] with a PERMUTED kv order inside every 64-block:
//   stored = (i>>1)*32 + lq*8 + (i&1)*4 + r   for original sb = i*16+lq*4+r.
//
// Operand-SWAPPED MFMA for z<2 (round-9): the old Q/K epilogue issued 64
// scalar 2-byte stores per thread; swapping mfma(W-frag, X-frag) transposes
// C so reg r runs along d (contiguous in Q/K) -> 16x 8B bf16x4 stores,
// f32x4 bias loads, h uniform/wave.  z==2 keeps the old orientation.
// XCD-chunked swizzle (round-8) kept: swz = (id&7)*288 + id>>3.
__global__ __launch_bounds__(256) void qkv_gemm(
    const bf16_t* __restrict__ Xb, const bf16_t* __restrict__ Wb,
    const float* __restrict__ bq, const float* __restrict__ bk,
    const float* __restrict__ bv,
    bf16_t* __restrict__ Q, bf16_t* __restrict__ K, bf16_t* __restrict__ VT) {
  __shared__ alignas(16) bf16_t ldsA[2][128 * 32];
  __shared__ alignas(16) bf16_t ldsB[2][128 * 32];

  const int t = threadIdx.x;
  const int w = t >> 6, l = t & 63, lr = l & 15, lq = l >> 4;
  const int wr = w >> 1, wc = w & 1;

  const int id = blockIdx.x;
  const int swz = (id & 7) * 288 + (id >> 3);       // XCD-chunked remap
  const int z = swz / 768;
  const int rem = swz - z * 768;
  const int m0 = (rem / 6) * 128, n0 = (rem % 6) * 128;

  const bf16_t* W = Wb + z * NW;
  const float* bias = (z == 0) ? bq : (z == 1) ? bk : bv;
  // Q carries the softmax scale 0.125 and the exp2 conversion log2(e):
  const float osc = (z == 0) ? 0.1803368801f : 1.0f;

  const int sl0 = t, sl1 = t + 256;
  const int ra0 = sl0 >> 2, qa0 = (sl0 & 3) ^ swz4(ra0);
  const int ra1 = sl1 >> 2, qa1 = (sl1 & 3) ^ swz4(ra1);
  const bf16_t* A0 = Xb + (m0 + ra0) * HH + qa0 * 8;
  const bf16_t* A1 = Xb + (m0 + ra1) * HH + qa1 * 8;
  const bf16_t* B0 = W + (n0 + ra0) * HH + qa0 * 8;
  const bf16_t* B1 = W + (n0 + ra1) * HH + qa1 * 8;

  f32x4 acc[4][4] = {};

  // offA: X-panel fragment offsets (m rows, wr); offB: W-panel (n rows, wc)
  int offA[4], offB[4];
#pragma unroll
  for (int i = 0; i < 4; ++i) {
    int Ra = wr * 64 + i * 16 + lr;
    offA[i] = (Ra * 4 + (lq ^ swz4(Ra))) * 8;
    int Rb = wc * 64 + i * 16 + lr;
    offB[i] = (Rb * 4 + (lq ^ swz4(Rb))) * 8;
  }

  // Operand selection: mfma(op0, op1): D row(lq,r) <- op0 rows, col(lr) <- op1.
  // z==2: op0 = X (row=m), op1 = W (col=n)  [V^T epilogue needs r along s=m]
  // z<2 : op0 = W (row=n), op1 = X (col=m)  [Q/K epilogue: r along d=n]
  const bool zv = (z == 2);
  const bf16_t* LI = zv ? &ldsA[0][0] : &ldsB[0][0];
  const bf16_t* LJ = zv ? &ldsB[0][0] : &ldsA[0][0];
  int offI[4], offJ[4];
#pragma unroll
  for (int i = 0; i < 4; ++i) {
    offI[i] = zv ? offA[i] : offB[i];
    offJ[i] = zv ? offB[i] : offA[i];
  }

  auto stage = [&](int buf, int kt) {
    int ko = kt * 32;
    gl_lds16(A0 + ko, ldsA[buf] + sl0 * 8);
    gl_lds16(A1 + ko, ldsA[buf] + sl1 * 8);
    gl_lds16(B0 + ko, ldsB[buf] + sl0 * 8);
    gl_lds16(B1 + ko, ldsB[buf] + sl1 * 8);
  };

  auto compute = [&](const int buf) {
    bf16x8 fa[4], fb[4];
#pragma unroll
    for (int i = 0; i < 4; ++i) fa[i] = *(const bf16x8*)(LI + buf * 4096 + offI[i]);
#pragma unroll
    for (int j = 0; j < 4; ++j) fb[j] = *(const bf16x8*)(LJ + buf * 4096 + offJ[j]);
#pragma unroll
    for (int i = 0; i < 4; ++i)
#pragma unroll
      for (int j = 0; j < 4; ++j)
        acc[i][j] = __builtin_amdgcn_mfma_f32_16x16x32_bf16(fa[i], fb[j], acc[i][j], 0, 0, 0);
  };

  stage(0, 0);
  __syncthreads();     // tile0 drained
  stage(1, 1);         // in flight under compute(0)
  compute(0);
  for (int kt = 1; kt < 23; kt += 2) {
    __syncthreads();   // drains stage(buf1,kt); all waves done with buf0
    stage(0, kt + 1);
    compute(1);
    __syncthreads();   // drains stage(buf0,kt+1); all waves done with buf1
    stage(1, kt + 2);
    compute(0);
  }
  __syncthreads();     // drains stage(buf1,23)
  compute(1);

  const int mb = m0 + wr * 64, nb = n0 + wc * 64;
  if (zv) {
    // ---- V^T epilogue (row=m via lq,r; col=n via lr) -- unchanged ----
#pragma unroll
    for (int j = 0; j < 4; ++j) {
      int n = nb + j * 16 + lr;
      int h = n >> 6, d = n & 63;
      float bbias = bias[n];
#pragma unroll
      for (int i = 0; i < 4; ++i) {
        int mrow = mb + i * 16 + lq * 4;
        int b = mrow >> 11, s = mrow & 2047;
        bf16x4 pk;
#pragma unroll
        for (int r = 0; r < 4; ++r) pk[r] = (bf16_t)(acc[i][j][r] + bbias);
        // permuted kv order within the 64-block (see header comment)
        int sperm = (s & ~63) + ((i >> 1) << 5) + (lq << 3) + ((i & 1) << 2);
        *(bf16x4*)(VT + ((size_t)(b * NHH + h) * HD + d) * SS + sperm) = pk;
      }
    }
  } else {
    // ---- Q/K epilogue (row=n via lq,r; col=m via lr): vector stores ----
    bf16_t* O = (z == 0) ? Q : K;
    const int h = nb >> 6;                 // uniform per wave (nb mult of 64)
#pragma unroll
    for (int j = 0; j < 4; ++j) {          // j indexes m-subblocks (op1)
      int mrow = mb + j * 16 + lr;
      int b = mrow >> 11, s = mrow & 2047;
      bf16_t* orow = O + ((size_t)(b * NHH + h) * SS + s) * HD;
#pragma unroll
      for (int i = 0; i < 4; ++i) {        // i indexes n-subblocks (op0)
        int dq = i * 16 + lq * 4;          // d quad within head
        f32x4 bi = *(const f32x4*)(bias + nb + dq);
        bf16x4 pk;
#pragma unroll
        for (int r = 0; r < 4; ++r) pk[r] = (bf16_t)((acc[i][j][r] + bi[r]) * osc);
        *(bf16x4*)(orow + dq) = pk;
      }
    }
  }
}

// ============ kernel 3: flash attention (all-x32 MFMA, zero-cost P re-layout) ============
// Round-7 verified: x32-only MFMA + permuted-V register-concat P, bank
// conflicts = 0, FETCH = ideal 69 MB, both pipes ~36%, 138.7us.
// launch_bounds(256,4) -> 128-VGPR cap, kernel sits at 64 VGPR, no spill.
// DO NOT use (256,5): two probes (r1, r9) both forced VGPR to 48 (HW
// allocation quantum) -> 500+ MB scratch spill, 2.4x slower.
__global__ __launch_bounds__(256, 4) void flash_kernel(
    const bf16_t* __restrict__ Q, const bf16_t* __restrict__ K,
    const bf16_t* __restrict__ VT, const float* __restrict__ mask,
    float* __restrict__ out) {
  // [buf][0] = K tile (64x64), [buf][1] = V^T tile (64x64).  32768 B total.
  __shared__ alignas(16) bf16_t ldsKV[2][2][64 * 64];

  const int t = threadIdx.x;
  const int w = t >> 6, l = t & 63, lr = l & 15, lq = l >> 4;
  const int rs7 = lr & 7;
  const int bh = blockIdx.x % 96, b = bh / NHH, h = bh - b * NHH;
  const int s0 = (blockIdx.x / 96) * 128;
  const bf16_t* Qb = Q + ((size_t)bh * SS + s0) * HD;
  const bf16_t* Kb = K + (size_t)bh * SS * HD;
  const bf16_t* Vb = VT + (size_t)bh * HD * SS;
  const float* mb = mask + b * SS;

  // ---- stage Q (128x64 = 16 KB) into the buf0 region, 8-chunk xor swizzle ----
  bf16_t* qs = &ldsKV[0][0][0];
#pragma unroll
  for (int i = 0; i < 4; ++i) {
    int sl = t + i * 256;
    int r = sl >> 3, q = (sl & 7) ^ (r & 7);
    gl_lds16(Qb + r * HD + q * 8, qs + sl * 8);
  }
  __syncthreads();   // Q staged

  bf16x8 aq0[2], aq1[2];
#pragma unroll
  for (int qi = 0; qi < 2; ++qi) {
    int Rq = w * 32 + qi * 16 + lr;
    aq0[qi] = *(const bf16x8*)(qs + (Rq * 8 + (lq ^ (Rq & 7))) * 8);
    aq1[qi] = *(const bf16x8*)(qs + (Rq * 8 + ((lq + 4) ^ (Rq & 7))) * 8);
  }
  __syncthreads();   // all waves hold Q in registers; buf0 region reusable

  const int c0 = t, c1 = t + 256;
  const int cr0 = c0 >> 3, cq0 = (c0 & 7) ^ (cr0 & 7);
  const int cr1 = c1 >> 3, cq1 = (c1 & 7) ^ (cr1 & 7);

  auto stage = [&](int buf, int kt) {
    const bf16_t* ks = Kb + kt * 64 * HD;
    gl_lds16(ks + cr0 * HD + cq0 * 8, ldsKV[buf][0] + c0 * 8);
    gl_lds16(ks + cr1 * HD + cq1 * 8, ldsKV[buf][0] + c1 * 8);
    gl_lds16(Vb + cr0 * SS + kt * 64 + cq0 * 8, ldsKV[buf][1] + c0 * 8);
    gl_lds16(Vb + cr1 * SS + kt * 64 + cq1 * 8, ldsKV[buf][1] + c1 * 8);
  };

  // ---- per-lane LDS byte bases (loop-invariant; reads = base + imm) ----
  // K: row Rk = j*16+lr, chunk lq / lq+4 (xor rs7), + j*2048
  const char* LB = (const char*)&ldsKV[0][0][0];
  const int kb0 = lr * 128 + ((lq ^ rs7) * 16);
  const int kb1 = lr * 128 + (((lq + 4) ^ rs7) * 16);
  // V (x32 A-frag): row d = dt*16+lr, stored-octet chunk gi*4+lq (xor rs7)
  int vg[2];
#pragma unroll
  for (int g = 0; g < 2; ++g) vg[g] = lr * 128 + (((g * 4 + lq) ^ rs7) * 16);

  f32x4 O[2][4] = {};
  f32x4 Lacc[2] = {};
  bf16x8 ones8;
#pragma unroll
  for (int r = 0; r < 8; ++r) ones8[r] = (bf16_t)1.0f;

  const float L2E = 1.44269504f;

  // BUFB: byte offset of the double-buffer half (0 or 16384) — literal at call sites.
  auto compute = [&](const int BUFB, int kt) {
    const char* Kbase = LB + BUFB;
    const char* Vbase = LB + BUFB + 8192;

#pragma unroll
    for (int gi = 0; gi < 2; ++gi) {
      bf16x8 pf[2];   // per qi: x32 B-frag octet = concat of quads j=2gi, 2gi+1
#pragma unroll
      for (int jj = 0; jj < 2; ++jj) {
        const int j = gi * 2 + jj;
        bf16x8 k0 = *(const bf16x8*)(Kbase + kb0 + j * 2048);
        bf16x8 k1 = *(const bf16x8*)(Kbase + kb1 + j * 2048);
        f32x4 mvv = *(const f32x4*)(mb + kt * 64 + j * 16 + lq * 4);
        f32x4 marg = mvv * L2E;
#pragma unroll
        for (int qi = 0; qi < 2; ++qi) {
          f32x4 st = mfma32(k0, aq0[qi], marg);
          st = mfma32(k1, aq1[qi], st);
#pragma unroll
          for (int r = 0; r < 4; ++r)
            pf[qi][jj * 4 + r] = (bf16_t)__builtin_amdgcn_exp2f(st[r]);
        }
      }
      // ---- l += 1^T . P^T  (K=32, MFMA pipe) ----
      Lacc[0] = mfma32(ones8, pf[0], Lacc[0]);
      Lacc[1] = mfma32(ones8, pf[1], Lacc[1]);
      // ---- O^T += V^T . P^T  (K=32, V in permuted-stored order) ----
#pragma unroll
      for (int dt = 0; dt < 4; ++dt) {
        bf16x8 av = *(const bf16x8*)(Vbase + vg[gi] + dt * 2048);
        O[0][dt] = mfma32(av, pf[0], O[0][dt]);
        O[1][dt] = mfma32(av, pf[1], O[1][dt]);
      }
    }
  };

  stage(0, 0);
  __syncthreads();   // tile0 drained
  stage(1, 1);       // in flight under compute(0)
  compute(0, 0);
  for (int kt = 1; kt < 31; kt += 2) {
    __syncthreads();               // drains stage of buf1(kt); all waves done with buf0
    stage(0, kt + 1);
    compute(16384, kt);
    __syncthreads();               // drains stage of buf0(kt+1); all done with buf1
    stage(1, kt + 2);
    compute(0, kt + 1);
  }
  __syncthreads();
  compute(16384, 31);

  // ---- epilogue: inv from MFMA row-sum (no shuffles) ----
#pragma unroll
  for (int qi = 0; qi < 2; ++qi) {
    float inv = 1.0f / Lacc[qi][0];
    int srow = s0 + w * 32 + qi * 16 + lr;
    float* op = out + ((size_t)b * SS + srow) * HH + h * HD;
#pragma unroll
    for (int dt = 0; dt < 4; ++dt) {
      f32x4 o = O[qi][dt];
      o *= inv;
      *(f32x4*)(op + dt * 16 + lq * 4) = o;
    }
  }
}

// ============ launcher ============
extern "C" void kernel_launch(void* const* d_in, const int* in_sizes, int n_in,
                              void* d_out, int out_size, void* d_ws, size_t ws_size,
                              hipStream_t stream) {
  const float* X    = (const float*)d_in[0];
  const float* mask = (const float*)d_in[1];
  const float* Wq   = (const float*)d_in[2];
  const float* bq   = (const float*)d_in[3];
  const float* Wk   = (const float*)d_in[4];
  const float* bk   = (const float*)d_in[5];
  const float* Wv   = (const float*)d_in[6];
  const float* bv   = (const float*)d_in[7];
  float* out = (float*)d_out;

  char* ws = (char*)d_ws;
  bf16_t* Xb = (bf16_t*)(ws);                        // 25165824 B
  bf16_t* Wb = (bf16_t*)(ws + 25165824);             //  3538944 B
  bf16_t* Qb = (bf16_t*)(ws + 28704768);             // 25165824 B
  bf16_t* Kb = (bf16_t*)(ws + 53870592);             // 25165824 B
  bf16_t* VT = (bf16_t*)(ws + 79036416);             // 25165824 B

  cvt_kernel<<<14016, 256, 0, stream>>>(X, Wq, Wk, Wv, Xb, Wb);
  qkv_gemm<<<2304, 256, 0, stream>>>(Xb, Wb, bq, bk, bv, Qb, Kb, VT);
  flash_kernel<<<1536, 256, 0, stream>>>(Qb, Kb, VT, mask, out);
}

// Round 12
// 303.818 us; speedup vs baseline: 1.7049x; 1.0750x over previous
//
#include <hip/hip_runtime.h>

typedef __bf16 bf16_t;
typedef __bf16 bf16x8 __attribute__((ext_vector_type(8)));
typedef __bf16 bf16x4 __attribute__((ext_vector_type(4)));
typedef float  f32x4  __attribute__((ext_vector_type(4)));
typedef short  s16x4  __attribute__((ext_vector_type(4)));

#define DEV __device__ __forceinline__

// ---- constants ----
#define BB 8
#define SS 2048
#define HH 768
#define NHH 12
#define HD 64
#define NX (BB*SS*HH)      // 12582912
#define NW (HH*HH)         // 589824

// async global->LDS, 16B per lane; LDS dest must be wave-uniform base + lane*16
DEV void gl_lds16(const void* g, void* s) {
  __builtin_amdgcn_global_load_lds(
      (__attribute__((address_space(1))) void*)(void*)g,
      (__attribute__((address_space(3))) void*)s, 16, 0, 0);
}

DEV int swz4(int r) { return (r ^ (r >> 2)) & 3; }   // 4-chunk (64B) rows

DEV f32x4 mfma32(bf16x8 a, bf16x8 b, f32x4 c) {
  return __builtin_amdgcn_mfma_f32_16x16x32_bf16(a, b, c, 0, 0, 0);
}

// ============ kernel 1: fp32 -> bf16 conversion (X, Wq, Wk, Wv) ============
__global__ __launch_bounds__(256) void cvt_kernel(
    const float* __restrict__ X, const float* __restrict__ Wq,
    const float* __restrict__ Wk, const float* __restrict__ Wv,
    bf16_t* __restrict__ Xb, bf16_t* __restrict__ Wb) {
  int idx = (blockIdx.x * 256 + threadIdx.x) * 4;
  const float* src;
  bf16_t* dst;
  if (idx < NX) { src = X + idx; dst = Xb + idx; }
  else {
    int j = idx - NX;
    int w = j / NW;
    int jj = j - w * NW;
    src = (w == 0 ? Wq : (w == 1 ? Wk : Wv)) + jj;
    dst = Wb + j;
  }
  float4 v = *(const float4*)src;
  bf16x4 o;
  o[0] = (bf16_t)v.x; o[1] = (bf16_t)v.y; o[2] = (bf16_t)v.z; o[3] = (bf16_t)v.w;
  *(bf16x4*)dst = o;
}

// ============ kernel 2: fused QKV projection GEMM ============
// z=0 -> Q [b][h][s][d] PRE-SCALED by 0.125*log2(e), z=1 -> K
// z=2 -> V^T [b][h][d][s] with a PERMUTED kv order inside every 64-block:
//   stored = (i>>1)*32 + lq*8 + (i&1)*4 + r   for original sb = i*16+lq*4+r.
//
// Round-11: epilogue-through-LDS.  r8 (64x 2B semi-coalesced stores) and r10
// (16x 8B stores at 128B stride = 64 txn/inst) are both store-bound.  Now the
// 32KB staging LDS (dead after the last K-step; A and B merged into ONE
// buffer so it can alias) is reused as the 128x128 bf16 output tile:
//   phase 1: 16x ds_write_b64 (bias applied; quad along tile fast axis --
//            swapped mfma for z<2, natural for z==2; 16B-chunk XOR swizzle)
//   phase 2: 8x ds_read_b128 + 8x 16B FULLY-COALESCED global stores
// V^T's kv-permutation is folded into the tile write; readback is contiguous.
// XCD-chunked swizzle (round-8) kept: swz = (id&7)*288 + id>>3.
__global__ __launch_bounds__(256) void qkv_gemm(
    const bf16_t* __restrict__ Xb, const bf16_t* __restrict__ Wb,
    const float* __restrict__ bq, const float* __restrict__ bk,
    const float* __restrict__ bv,
    bf16_t* __restrict__ Q, bf16_t* __restrict__ K, bf16_t* __restrict__ VT) {
  // [0:4096) A buf0 | [4096:8192) A buf1 | [8192:12288) B buf0 | [12288:16384) B buf1
  // (elems).  Reused whole as the 128x128 bf16 epilogue tile (32 KB).
  __shared__ alignas(16) bf16_t ldsAll[16384];

  const int t = threadIdx.x;
  const int w = t >> 6, l = t & 63, lr = l & 15, lq = l >> 4;
  const int wr = w >> 1, wc = w & 1;

  const int id = blockIdx.x;
  const int swz = (id & 7) * 288 + (id >> 3);       // XCD-chunked remap
  const int z = swz / 768;
  const int rem = swz - z * 768;
  const int m0 = (rem / 6) * 128, n0 = (rem % 6) * 128;

  const bf16_t* W = Wb + z * NW;
  const float* bias = (z == 0) ? bq : (z == 1) ? bk : bv;
  // Q carries the softmax scale 0.125 and the exp2 conversion log2(e):
  const float osc = (z == 0) ? 0.1803368801f : 1.0f;

  const int sl0 = t, sl1 = t + 256;
  const int ra0 = sl0 >> 2, qa0 = (sl0 & 3) ^ swz4(ra0);
  const int ra1 = sl1 >> 2, qa1 = (sl1 & 3) ^ swz4(ra1);
  const bf16_t* A0 = Xb + (m0 + ra0) * HH + qa0 * 8;
  const bf16_t* A1 = Xb + (m0 + ra1) * HH + qa1 * 8;
  const bf16_t* B0 = W + (n0 + ra0) * HH + qa0 * 8;
  const bf16_t* B1 = W + (n0 + ra1) * HH + qa1 * 8;

  f32x4 acc[4][4] = {};

  // offA: X-panel fragment offsets (m rows, wr); offB: W-panel (n rows, wc)
  int offA[4], offB[4];
#pragma unroll
  for (int i = 0; i < 4; ++i) {
    int Ra = wr * 64 + i * 16 + lr;
    offA[i] = (Ra * 4 + (lq ^ swz4(Ra))) * 8;
    int Rb = wc * 64 + i * 16 + lr;
    offB[i] = (Rb * 4 + (lq ^ swz4(Rb))) * 8;
  }

  // Operand selection: mfma(op0, op1): D row(lq,r) <- op0 rows, col(lr) <- op1.
  // z==2: op0 = X (row=m), op1 = W (col=n)  [tile quad along m=s, V^T fast axis]
  // z<2 : op0 = W (row=n), op1 = X (col=m)  [tile quad along n=d, Q/K fast axis]
  const bool zv = (z == 2);
  const bf16_t* LI = zv ? ldsAll : ldsAll + 8192;
  const bf16_t* LJ = zv ? ldsAll + 8192 : ldsAll;
  int offI[4], offJ[4];
#pragma unroll
  for (int i = 0; i < 4; ++i) {
    offI[i] = zv ? offA[i] : offB[i];
    offJ[i] = zv ? offB[i] : offA[i];
  }

  auto stage = [&](int buf, int kt) {
    int ko = kt * 32;
    bf16_t* LA = ldsAll + buf * 4096;
    bf16_t* LB = ldsAll + 8192 + buf * 4096;
    gl_lds16(A0 + ko, LA + sl0 * 8);
    gl_lds16(A1 + ko, LA + sl1 * 8);
    gl_lds16(B0 + ko, LB + sl0 * 8);
    gl_lds16(B1 + ko, LB + sl1 * 8);
  };

  auto compute = [&](const int buf) {
    bf16x8 fa[4], fb[4];
#pragma unroll
    for (int i = 0; i < 4; ++i) fa[i] = *(const bf16x8*)(LI + buf * 4096 + offI[i]);
#pragma unroll
    for (int j = 0; j < 4; ++j) fb[j] = *(const bf16x8*)(LJ + buf * 4096 + offJ[j]);
#pragma unroll
    for (int i = 0; i < 4; ++i)
#pragma unroll
      for (int j = 0; j < 4; ++j)
        acc[i][j] = __builtin_amdgcn_mfma_f32_16x16x32_bf16(fa[i], fb[j], acc[i][j], 0, 0, 0);
  };

  stage(0, 0);
  __syncthreads();     // tile0 drained
  stage(1, 1);         // in flight under compute(0)
  compute(0);
  for (int kt = 1; kt < 23; kt += 2) {
    __syncthreads();   // drains stage(buf1,kt); all waves done with buf0
    stage(0, kt + 1);
    compute(1);
    __syncthreads();   // drains stage(buf0,kt+1); all waves done with buf1
    stage(1, kt + 2);
    compute(0);
  }
  __syncthreads();     // drains stage(buf1,23)
  compute(1);

  // ======== epilogue through LDS ========
  __syncthreads();     // all waves done reading staging buffers
  char* T = (char*)ldsAll;   // 128 rows x 256 B (16 chunks of 16 B), XOR-swizzled

  if (zv) {
    // ---- tile [n=row][m_stored], quad along m (natural orientation) ----
#pragma unroll
    for (int j = 0; j < 4; ++j) {
      int row = wc * 64 + j * 16 + lr;                 // n_tile
      float bbias = bias[n0 + row];
#pragma unroll
      for (int i = 0; i < 4; ++i) {
        int chunkC = wr * 8 + (i >> 1) * 4 + lq;       // (m_stored quad)>>3
        int byteoff = row * 256 + ((chunkC ^ (row & 15)) * 16) + (i & 1) * 8;
        bf16x4 pk;
#pragma unroll
        for (int r = 0; r < 4; ++r) pk[r] = (bf16_t)(acc[i][j][r] + bbias);
        *(bf16x4*)(T + byteoff) = pk;
      }
    }
  } else {
    // ---- tile [m=row][n], quad along n (swapped orientation) ----
#pragma unroll
    for (int j = 0; j < 4; ++j) {
      int row = wr * 64 + j * 16 + lr;                 // m_tile
#pragma unroll
      for (int i = 0; i < 4; ++i) {
        int nq = wc * 64 + i * 16 + lq * 4;            // n quad base
        f32x4 bi = *(const f32x4*)(bias + n0 + nq);
        int chunkC = nq >> 3;
        int byteoff = row * 256 + ((chunkC ^ (row & 15)) * 16) + (lq & 1) * 8;
        bf16x4 pk;
#pragma unroll
        for (int r = 0; r < 4; ++r) pk[r] = (bf16_t)((acc[i][j][r] + bi[r]) * osc);
        *(bf16x4*)(T + byteoff) = pk;
      }
    }
  }
  __syncthreads();

  // ---- phase 2: 8x (ds_read_b128 + coalesced 16B global store) ----
  const int b = m0 >> 11, sbase = m0 & 2047;
  if (zv) {
#pragma unroll
    for (int it = 0; it < 8; ++it) {
      int flat = it * 256 + t;
      int row = flat >> 4, k = flat & 15;
      bf16x8 v = *(const bf16x8*)(T + row * 256 + ((k ^ (row & 15)) * 16));
      int n = n0 + row, h = n >> 6, d = n & 63;
      *(bf16x8*)(VT + ((size_t)(b * NHH + h) * HD + d) * SS + sbase + k * 8) = v;
    }
  } else {
    bf16_t* O = (z == 0) ? Q : K;
    const int h0 = n0 >> 6;
#pragma unroll
    for (int it = 0; it < 8; ++it) {
      int flat = it * 256 + t;
      int row = flat >> 4, k = flat & 15;
      bf16x8 v = *(const bf16x8*)(T + row * 256 + ((k ^ (row & 15)) * 16));
      *(bf16x8*)(O + ((size_t)(b * NHH + h0 + (k >> 3)) * SS + sbase + row) * HD + (k & 7) * 8) = v;
    }
  }
}

// ============ kernel 3: flash attention (all-x32 MFMA, zero-cost P re-layout) ============
// Round-7 verified: x32-only MFMA + permuted-V register-concat P, bank
// conflicts = 0, FETCH = ideal 69 MB, both pipes ~36%, 138.7us.
// launch_bounds(256,4) -> 128-VGPR cap, kernel sits at 64 VGPR, no spill.
// DO NOT use (256,5): two probes (r1, r9) both forced VGPR to 48 (HW
// allocation quantum) -> 500+ MB scratch spill, 2.4x slower.
__global__ __launch_bounds__(256, 4) void flash_kernel(
    const bf16_t* __restrict__ Q, const bf16_t* __restrict__ K,
    const bf16_t* __restrict__ VT, const float* __restrict__ mask,
    float* __restrict__ out) {
  // [buf][0] = K tile (64x64), [buf][1] = V^T tile (64x64).  32768 B total.
  __shared__ alignas(16) bf16_t ldsKV[2][2][64 * 64];

  const int t = threadIdx.x;
  const int w = t >> 6, l = t & 63, lr = l & 15, lq = l >> 4;
  const int rs7 = lr & 7;
  const int bh = blockIdx.x % 96, b = bh / NHH, h = bh - b * NHH;
  const int s0 = (blockIdx.x / 96) * 128;
  const bf16_t* Qb = Q + ((size_t)bh * SS + s0) * HD;
  const bf16_t* Kb = K + (size_t)bh * SS * HD;
  const bf16_t* Vb = VT + (size_t)bh * HD * SS;
  const float* mb = mask + b * SS;

  // ---- stage Q (128x64 = 16 KB) into the buf0 region, 8-chunk xor swizzle ----
  bf16_t* qs = &ldsKV[0][0][0];
#pragma unroll
  for (int i = 0; i < 4; ++i) {
    int sl = t + i * 256;
    int r = sl >> 3, q = (sl & 7) ^ (r & 7);
    gl_lds16(Qb + r * HD + q * 8, qs + sl * 8);
  }
  __syncthreads();   // Q staged

  bf16x8 aq0[2], aq1[2];
#pragma unroll
  for (int qi = 0; qi < 2; ++qi) {
    int Rq = w * 32 + qi * 16 + lr;
    aq0[qi] = *(const bf16x8*)(qs + (Rq * 8 + (lq ^ (Rq & 7))) * 8);
    aq1[qi] = *(const bf16x8*)(qs + (Rq * 8 + ((lq + 4) ^ (Rq & 7))) * 8);
  }
  __syncthreads();   // all waves hold Q in registers; buf0 region reusable

  const int c0 = t, c1 = t + 256;
  const int cr0 = c0 >> 3, cq0 = (c0 & 7) ^ (cr0 & 7);
  const int cr1 = c1 >> 3, cq1 = (c1 & 7) ^ (cr1 & 7);

  auto stage = [&](int buf, int kt) {
    const bf16_t* ks = Kb + kt * 64 * HD;
    gl_lds16(ks + cr0 * HD + cq0 * 8, ldsKV[buf][0] + c0 * 8);
    gl_lds16(ks + cr1 * HD + cq1 * 8, ldsKV[buf][0] + c1 * 8);
    gl_lds16(Vb + cr0 * SS + kt * 64 + cq0 * 8, ldsKV[buf][1] + c0 * 8);
    gl_lds16(Vb + cr1 * SS + kt * 64 + cq1 * 8, ldsKV[buf][1] + c1 * 8);
  };

  // ---- per-lane LDS byte bases (loop-invariant; reads = base + imm) ----
  // K: row Rk = j*16+lr, chunk lq / lq+4 (xor rs7), + j*2048
  const char* LB = (const char*)&ldsKV[0][0][0];
  const int kb0 = lr * 128 + ((lq ^ rs7) * 16);
  const int kb1 = lr * 128 + (((lq + 4) ^ rs7) * 16);
  // V (x32 A-frag): row d = dt*16+lr, stored-octet chunk gi*4+lq (xor rs7)
  int vg[2];
#pragma unroll
  for (int g = 0; g < 2; ++g) vg[g] = lr * 128 + (((g * 4 + lq) ^ rs7) * 16);

  f32x4 O[2][4] = {};
  f32x4 Lacc[2] = {};
  bf16x8 ones8;
#pragma unroll
  for (int r = 0; r < 8; ++r) ones8[r] = (bf16_t)1.0f;

  const float L2E = 1.44269504f;

  // BUFB: byte offset of the double-buffer half (0 or 16384) — literal at call sites.
  auto compute = [&](const int BUFB, int kt) {
    const char* Kbase = LB + BUFB;
    const char* Vbase = LB + BUFB + 8192;

#pragma unroll
    for (int gi = 0; gi < 2; ++gi) {
      bf16x8 pf[2];   // per qi: x32 B-frag octet = concat of quads j=2gi, 2gi+1
#pragma unroll
      for (int jj = 0; jj < 2; ++jj) {
        const int j = gi * 2 + jj;
        bf16x8 k0 = *(const bf16x8*)(Kbase + kb0 + j * 2048);
        bf16x8 k1 = *(const bf16x8*)(Kbase + kb1 + j * 2048);
        f32x4 mvv = *(const f32x4*)(mb + kt * 64 + j * 16 + lq * 4);
        f32x4 marg = mvv * L2E;
#pragma unroll
        for (int qi = 0; qi < 2; ++qi) {
          f32x4 st = mfma32(k0, aq0[qi], marg);
          st = mfma32(k1, aq1[qi], st);
#pragma unroll
          for (int r = 0; r < 4; ++r)
            pf[qi][jj * 4 + r] = (bf16_t)__builtin_amdgcn_exp2f(st[r]);
        }
      }
      // ---- l += 1^T . P^T  (K=32, MFMA pipe) ----
      Lacc[0] = mfma32(ones8, pf[0], Lacc[0]);
      Lacc[1] = mfma32(ones8, pf[1], Lacc[1]);
      // ---- O^T += V^T . P^T  (K=32, V in permuted-stored order) ----
#pragma unroll
      for (int dt = 0; dt < 4; ++dt) {
        bf16x8 av = *(const bf16x8*)(Vbase + vg[gi] + dt * 2048);
        O[0][dt] = mfma32(av, pf[0], O[0][dt]);
        O[1][dt] = mfma32(av, pf[1], O[1][dt]);
      }
    }
  };

  stage(0, 0);
  __syncthreads();   // tile0 drained
  stage(1, 1);       // in flight under compute(0)
  compute(0, 0);
  for (int kt = 1; kt < 31; kt += 2) {
    __syncthreads();               // drains stage of buf1(kt); all waves done with buf0
    stage(0, kt + 1);
    compute(16384, kt);
    __syncthreads();               // drains stage of buf0(kt+1); all done with buf1
    stage(1, kt + 2);
    compute(0, kt + 1);
  }
  __syncthreads();
  compute(16384, 31);

  // ---- epilogue: inv from MFMA row-sum (no shuffles) ----
#pragma unroll
  for (int qi = 0; qi < 2; ++qi) {
    float inv = 1.0f / Lacc[qi][0];
    int srow = s0 + w * 32 + qi * 16 + lr;
    float* op = out + ((size_t)b * SS + srow) * HH + h * HD;
#pragma unroll
    for (int dt = 0; dt < 4; ++dt) {
      f32x4 o = O[qi][dt];
      o *= inv;
      *(f32x4*)(op + dt * 16 + lq * 4) = o;
    }
  }
}

// ============ launcher ============
extern "C" void kernel_launch(void* const* d_in, const int* in_sizes, int n_in,
                              void* d_out, int out_size, void* d_ws, size_t ws_size,
                              hipStream_t stream) {
  const float* X    = (const float*)d_in[0];
  const float* mask = (const float*)d_in[1];
  const float* Wq   = (const float*)d_in[2];
  const float* bq   = (const float*)d_in[3];
  const float* Wk   = (const float*)d_in[4];
  const float* bk   = (const float*)d_in[5];
  const float* Wv   = (const float*)d_in[6];
  const float* bv   = (const float*)d_in[7];
  float* out = (float*)d_out;

  char* ws = (char*)d_ws;
  bf16_t* Xb = (bf16_t*)(ws);                        // 25165824 B
  bf16_t* Wb = (bf16_t*)(ws + 25165824);             //  3538944 B
  bf16_t* Qb = (bf16_t*)(ws + 28704768);             // 25165824 B
  bf16_t* Kb = (bf16_t*)(ws + 53870592);             // 25165824 B
  bf16_t* VT = (bf16_t*)(ws + 79036416);             // 25165824 B

  cvt_kernel<<<14016, 256, 0, stream>>>(X, Wq, Wk, Wv, Xb, Wb);
  qkv_gemm<<<2304, 256, 0, stream>>>(Xb, Wb, bq, bk, bv, Qb, Kb, VT);
  flash_kernel<<<1536, 256, 0, stream>>>(Qb, Kb, VT, mask, out);
}

// Round 13
// 297.339 us; speedup vs baseline: 1.7421x; 1.0218x over previous
//
#include <hip/hip_runtime.h>

typedef __bf16 bf16_t;
typedef __bf16 bf16x8 __attribute__((ext_vector_type(8)));
typedef __bf16 bf16x4 __attribute__((ext_vector_type(4)));
typedef float  f32x4  __attribute__((ext_vector_type(4)));
typedef short  s16x4  __attribute__((ext_vector_type(4)));

#define DEV __device__ __forceinline__

// ---- constants ----
#define BB 8
#define SS 2048
#define HH 768
#define NHH 12
#define HD 64
#define NX (BB*SS*HH)      // 12582912
#define NW (HH*HH)         // 589824

// async global->LDS, 16B per lane; LDS dest must be wave-uniform base + lane*16
DEV void gl_lds16(const void* g, void* s) {
  __builtin_amdgcn_global_load_lds(
      (__attribute__((address_space(1))) void*)(void*)g,
      (__attribute__((address_space(3))) void*)s, 16, 0, 0);
}

DEV int swz4(int r) { return (r ^ (r >> 2)) & 3; }   // 4-chunk (64B) rows

DEV f32x4 mfma32(bf16x8 a, bf16x8 b, f32x4 c) {
  return __builtin_amdgcn_mfma_f32_16x16x32_bf16(a, b, c, 0, 0, 0);
}

// ============ kernel 1: fp32 -> bf16 conversion (X, Wq, Wk, Wv) ============
__global__ __launch_bounds__(256) void cvt_kernel(
    const float* __restrict__ X, const float* __restrict__ Wq,
    const float* __restrict__ Wk, const float* __restrict__ Wv,
    bf16_t* __restrict__ Xb, bf16_t* __restrict__ Wb) {
  int idx = (blockIdx.x * 256 + threadIdx.x) * 4;
  const float* src;
  bf16_t* dst;
  if (idx < NX) { src = X + idx; dst = Xb + idx; }
  else {
    int j = idx - NX;
    int w = j / NW;
    int jj = j - w * NW;
    src = (w == 0 ? Wq : (w == 1 ? Wk : Wv)) + jj;
    dst = Wb + j;
  }
  float4 v = *(const float4*)src;
  bf16x4 o;
  o[0] = (bf16_t)v.x; o[1] = (bf16_t)v.y; o[2] = (bf16_t)v.z; o[3] = (bf16_t)v.w;
  *(bf16x4*)dst = o;
}

// ============ kernel 2: fused QKV projection GEMM ============
// z=0 -> Q [b][h][s][d] PRE-SCALED by 0.125*log2(e), z=1 -> K
// z=2 -> V^T [b][h][d][s] with a PERMUTED kv order inside every 64-block:
//   stored = (i>>1)*32 + lq*8 + (i&1)*4 + r   for original sb = i*16+lq*4+r.
// Epilogue-through-LDS (r12, verified: total 326.6 -> 303.8): staging LDS is
// reused as the 128x128 output tile; writes swizzled ds_write_b64, readback
// 8x ds_read_b128 + 8x fully-coalesced 16B global stores.
// XCD-chunked swizzle (r8): swz = (id&7)*288 + id>>3.
__global__ __launch_bounds__(256) void qkv_gemm(
    const bf16_t* __restrict__ Xb, const bf16_t* __restrict__ Wb,
    const float* __restrict__ bq, const float* __restrict__ bk,
    const float* __restrict__ bv,
    bf16_t* __restrict__ Q, bf16_t* __restrict__ K, bf16_t* __restrict__ VT) {
  // [0:4096) A buf0 | [4096:8192) A buf1 | [8192:12288) B buf0 | [12288:16384) B buf1
  // (elems).  Reused whole as the 128x128 bf16 epilogue tile (32 KB).
  __shared__ alignas(16) bf16_t ldsAll[16384];

  const int t = threadIdx.x;
  const int w = t >> 6, l = t & 63, lr = l & 15, lq = l >> 4;
  const int wr = w >> 1, wc = w & 1;

  const int id = blockIdx.x;
  const int swz = (id & 7) * 288 + (id >> 3);       // XCD-chunked remap
  const int z = swz / 768;
  const int rem = swz - z * 768;
  const int m0 = (rem / 6) * 128, n0 = (rem % 6) * 128;

  const bf16_t* W = Wb + z * NW;
  const float* bias = (z == 0) ? bq : (z == 1) ? bk : bv;
  // Q carries the softmax scale 0.125 and the exp2 conversion log2(e):
  const float osc = (z == 0) ? 0.1803368801f : 1.0f;

  const int sl0 = t, sl1 = t + 256;
  const int ra0 = sl0 >> 2, qa0 = (sl0 & 3) ^ swz4(ra0);
  const int ra1 = sl1 >> 2, qa1 = (sl1 & 3) ^ swz4(ra1);
  const bf16_t* A0 = Xb + (m0 + ra0) * HH + qa0 * 8;
  const bf16_t* A1 = Xb + (m0 + ra1) * HH + qa1 * 8;
  const bf16_t* B0 = W + (n0 + ra0) * HH + qa0 * 8;
  const bf16_t* B1 = W + (n0 + ra1) * HH + qa1 * 8;

  f32x4 acc[4][4] = {};

  // offA: X-panel fragment offsets (m rows, wr); offB: W-panel (n rows, wc)
  int offA[4], offB[4];
#pragma unroll
  for (int i = 0; i < 4; ++i) {
    int Ra = wr * 64 + i * 16 + lr;
    offA[i] = (Ra * 4 + (lq ^ swz4(Ra))) * 8;
    int Rb = wc * 64 + i * 16 + lr;
    offB[i] = (Rb * 4 + (lq ^ swz4(Rb))) * 8;
  }

  // Operand selection: mfma(op0, op1): D row(lq,r) <- op0 rows, col(lr) <- op1.
  // z==2: op0 = X (row=m), op1 = W (col=n)  [tile quad along m=s, V^T fast axis]
  // z<2 : op0 = W (row=n), op1 = X (col=m)  [tile quad along n=d, Q/K fast axis]
  const bool zv = (z == 2);
  const bf16_t* LI = zv ? ldsAll : ldsAll + 8192;
  const bf16_t* LJ = zv ? ldsAll + 8192 : ldsAll;
  int offI[4], offJ[4];
#pragma unroll
  for (int i = 0; i < 4; ++i) {
    offI[i] = zv ? offA[i] : offB[i];
    offJ[i] = zv ? offB[i] : offA[i];
  }

  auto stage = [&](int buf, int kt) {
    int ko = kt * 32;
    bf16_t* LA = ldsAll + buf * 4096;
    bf16_t* LB = ldsAll + 8192 + buf * 4096;
    gl_lds16(A0 + ko, LA + sl0 * 8);
    gl_lds16(A1 + ko, LA + sl1 * 8);
    gl_lds16(B0 + ko, LB + sl0 * 8);
    gl_lds16(B1 + ko, LB + sl1 * 8);
  };

  auto compute = [&](const int buf) {
    bf16x8 fa[4], fb[4];
#pragma unroll
    for (int i = 0; i < 4; ++i) fa[i] = *(const bf16x8*)(LI + buf * 4096 + offI[i]);
#pragma unroll
    for (int j = 0; j < 4; ++j) fb[j] = *(const bf16x8*)(LJ + buf * 4096 + offJ[j]);
#pragma unroll
    for (int i = 0; i < 4; ++i)
#pragma unroll
      for (int j = 0; j < 4; ++j)
        acc[i][j] = __builtin_amdgcn_mfma_f32_16x16x32_bf16(fa[i], fb[j], acc[i][j], 0, 0, 0);
  };

  stage(0, 0);
  __syncthreads();     // tile0 drained
  stage(1, 1);         // in flight under compute(0)
  compute(0);
  for (int kt = 1; kt < 23; kt += 2) {
    __syncthreads();   // drains stage(buf1,kt); all waves done with buf0
    stage(0, kt + 1);
    compute(1);
    __syncthreads();   // drains stage(buf0,kt+1); all waves done with buf1
    stage(1, kt + 2);
    compute(0);
  }
  __syncthreads();     // drains stage(buf1,23)
  compute(1);

  // ======== epilogue through LDS ========
  __syncthreads();     // all waves done reading staging buffers
  char* T = (char*)ldsAll;   // 128 rows x 256 B (16 chunks of 16 B), XOR-swizzled

  if (zv) {
    // ---- tile [n=row][m_stored], quad along m (natural orientation) ----
#pragma unroll
    for (int j = 0; j < 4; ++j) {
      int row = wc * 64 + j * 16 + lr;                 // n_tile
      float bbias = bias[n0 + row];
#pragma unroll
      for (int i = 0; i < 4; ++i) {
        int chunkC = wr * 8 + (i >> 1) * 4 + lq;       // (m_stored quad)>>3
        int byteoff = row * 256 + ((chunkC ^ (row & 15)) * 16) + (i & 1) * 8;
        bf16x4 pk;
#pragma unroll
        for (int r = 0; r < 4; ++r) pk[r] = (bf16_t)(acc[i][j][r] + bbias);
        *(bf16x4*)(T + byteoff) = pk;
      }
    }
  } else {
    // ---- tile [m=row][n], quad along n (swapped orientation) ----
#pragma unroll
    for (int j = 0; j < 4; ++j) {
      int row = wr * 64 + j * 16 + lr;                 // m_tile
#pragma unroll
      for (int i = 0; i < 4; ++i) {
        int nq = wc * 64 + i * 16 + lq * 4;            // n quad base
        f32x4 bi = *(const f32x4*)(bias + n0 + nq);
        int chunkC = nq >> 3;
        int byteoff = row * 256 + ((chunkC ^ (row & 15)) * 16) + (lq & 1) * 8;
        bf16x4 pk;
#pragma unroll
        for (int r = 0; r < 4; ++r) pk[r] = (bf16_t)((acc[i][j][r] + bi[r]) * osc);
        *(bf16x4*)(T + byteoff) = pk;
      }
    }
  }
  __syncthreads();

  // ---- phase 2: 8x (ds_read_b128 + coalesced 16B global store) ----
  const int b = m0 >> 11, sbase = m0 & 2047;
  if (zv) {
#pragma unroll
    for (int it = 0; it < 8; ++it) {
      int flat = it * 256 + t;
      int row = flat >> 4, k = flat & 15;
      bf16x8 v = *(const bf16x8*)(T + row * 256 + ((k ^ (row & 15)) * 16));
      int n = n0 + row, h = n >> 6, d = n & 63;
      *(bf16x8*)(VT + ((size_t)(b * NHH + h) * HD + d) * SS + sbase + k * 8) = v;
    }
  } else {
    bf16_t* O = (z == 0) ? Q : K;
    const int h0 = n0 >> 6;
#pragma unroll
    for (int it = 0; it < 8; ++it) {
      int flat = it * 256 + t;
      int row = flat >> 4, k = flat & 15;
      bf16x8 v = *(const bf16x8*)(T + row * 256 + ((k ^ (row & 15)) * 16));
      *(bf16x8*)(O + ((size_t)(b * NHH + h0 + (k >> 3)) * SS + sbase + row) * HD + (k & 7) * 8) = v;
    }
  }
}

// ============ kernel 3: flash attention (QBLK=256, 512 threads) ============
// Round-13: same per-wave inner loop as the verified r7 kernel (x32-only
// MFMA, permuted-V register-concat P, 0 bank conflicts), but 8 waves/block
// covering 256 q-rows.  Counters were stable at 36+36% issue, ~28% all-idle
// (barrier drain) with only 16 waves/CU.  Now: Q (256x64 = 32 KB) stages
// into the FULL K/V region during the prologue; K/V staging is 1 gl_lds16
// per tile (512 lanes x 16B = 8 KB); natural VGPR ~64 (per-wave code
// unchanged) -> 8 waves/SIMD -> 4 blocks x 8 waves = 32 waves/CU, and
// K/V L2->LDS staging traffic halves (768 blocks vs 1536).
// (512,4) = 128-VGPR cap, NO squeeze (r1/r9: forced caps below natural -> spill).
__global__ __launch_bounds__(512, 4) void flash_kernel(
    const bf16_t* __restrict__ Q, const bf16_t* __restrict__ K,
    const bf16_t* __restrict__ VT, const float* __restrict__ mask,
    float* __restrict__ out) {
  // [buf][0] = K tile (64x64), [buf][1] = V^T tile (64x64).  32768 B total.
  __shared__ alignas(16) bf16_t ldsKV[2][2][64 * 64];

  const int t = threadIdx.x;
  const int w = t >> 6, l = t & 63, lr = l & 15, lq = l >> 4;
  const int rs7 = lr & 7;
  const int bh = blockIdx.x % 96, b = bh / NHH, h = bh - b * NHH;
  const int s0 = (blockIdx.x / 96) * 256;
  const bf16_t* Qb = Q + ((size_t)bh * SS + s0) * HD;
  const bf16_t* Kb = K + (size_t)bh * SS * HD;
  const bf16_t* Vb = VT + (size_t)bh * HD * SS;
  const float* mb = mask + b * SS;

  // ---- stage Q (256x64 = 32 KB) into the WHOLE K/V region, xor swizzle ----
  bf16_t* qs = &ldsKV[0][0][0];
#pragma unroll
  for (int i = 0; i < 4; ++i) {
    int sl = t + i * 512;
    int r = sl >> 3, q = (sl & 7) ^ (r & 7);
    gl_lds16(Qb + r * HD + q * 8, qs + sl * 8);
  }
  __syncthreads();   // Q staged

  bf16x8 aq0[2], aq1[2];
#pragma unroll
  for (int qi = 0; qi < 2; ++qi) {
    int Rq = w * 32 + qi * 16 + lr;          // w in 0..7 -> rows 0..255
    aq0[qi] = *(const bf16x8*)(qs + (Rq * 8 + (lq ^ (Rq & 7))) * 8);
    aq1[qi] = *(const bf16x8*)(qs + (Rq * 8 + ((lq + 4) ^ (Rq & 7))) * 8);
  }
  __syncthreads();   // all waves hold Q in registers; region reusable for K/V

  const int cr = t >> 3, cq = (t & 7) ^ (cr & 7);   // 512 lanes = whole 8KB tile

  auto stage = [&](int buf, int kt) {
    gl_lds16(Kb + kt * 64 * HD + cr * HD + cq * 8, ldsKV[buf][0] + t * 8);
    gl_lds16(Vb + cr * SS + kt * 64 + cq * 8,      ldsKV[buf][1] + t * 8);
  };

  // ---- per-lane LDS byte bases (loop-invariant; reads = base + imm) ----
  // K: row Rk = j*16+lr, chunk lq / lq+4 (xor rs7), + j*2048
  const char* LB = (const char*)&ldsKV[0][0][0];
  const int kb0 = lr * 128 + ((lq ^ rs7) * 16);
  const int kb1 = lr * 128 + (((lq + 4) ^ rs7) * 16);
  // V (x32 A-frag): row d = dt*16+lr, stored-octet chunk gi*4+lq (xor rs7)
  int vg[2];
#pragma unroll
  for (int g = 0; g < 2; ++g) vg[g] = lr * 128 + (((g * 4 + lq) ^ rs7) * 16);

  f32x4 O[2][4] = {};
  f32x4 Lacc[2] = {};
  bf16x8 ones8;
#pragma unroll
  for (int r = 0; r < 8; ++r) ones8[r] = (bf16_t)1.0f;

  const float L2E = 1.44269504f;

  // BUFB: byte offset of the double-buffer half (0 or 16384) — literal at call sites.
  auto compute = [&](const int BUFB, int kt) {
    const char* Kbase = LB + BUFB;
    const char* Vbase = LB + BUFB + 8192;

#pragma unroll
    for (int gi = 0; gi < 2; ++gi) {
      bf16x8 pf[2];   // per qi: x32 B-frag octet = concat of quads j=2gi, 2gi+1
#pragma unroll
      for (int jj = 0; jj < 2; ++jj) {
        const int j = gi * 2 + jj;
        bf16x8 k0 = *(const bf16x8*)(Kbase + kb0 + j * 2048);
        bf16x8 k1 = *(const bf16x8*)(Kbase + kb1 + j * 2048);
        f32x4 mvv = *(const f32x4*)(mb + kt * 64 + j * 16 + lq * 4);
        f32x4 marg = mvv * L2E;
#pragma unroll
        for (int qi = 0; qi < 2; ++qi) {
          f32x4 st = mfma32(k0, aq0[qi], marg);
          st = mfma32(k1, aq1[qi], st);
#pragma unroll
          for (int r = 0; r < 4; ++r)
            pf[qi][jj * 4 + r] = (bf16_t)__builtin_amdgcn_exp2f(st[r]);
        }
      }
      // ---- l += 1^T . P^T  (K=32, MFMA pipe) ----
      Lacc[0] = mfma32(ones8, pf[0], Lacc[0]);
      Lacc[1] = mfma32(ones8, pf[1], Lacc[1]);
      // ---- O^T += V^T . P^T  (K=32, V in permuted-stored order) ----
#pragma unroll
      for (int dt = 0; dt < 4; ++dt) {
        bf16x8 av = *(const bf16x8*)(Vbase + vg[gi] + dt * 2048);
        O[0][dt] = mfma32(av, pf[0], O[0][dt]);
        O[1][dt] = mfma32(av, pf[1], O[1][dt]);
      }
    }
  };

  stage(0, 0);
  __syncthreads();   // tile0 drained
  stage(1, 1);       // in flight under compute(0)
  compute(0, 0);
  for (int kt = 1; kt < 31; kt += 2) {
    __syncthreads();               // drains stage of buf1(kt); all waves done with buf0
    stage(0, kt + 1);
    compute(16384, kt);
    __syncthreads();               // drains stage of buf0(kt+1); all done with buf1
    stage(1, kt + 2);
    compute(0, kt + 1);
  }
  __syncthreads();
  compute(16384, 31);

  // ---- epilogue: inv from MFMA row-sum (no shuffles) ----
#pragma unroll
  for (int qi = 0; qi < 2; ++qi) {
    float inv = 1.0f / Lacc[qi][0];
    int srow = s0 + w * 32 + qi * 16 + lr;
    float* op = out + ((size_t)b * SS + srow) * HH + h * HD;
#pragma unroll
    for (int dt = 0; dt < 4; ++dt) {
      f32x4 o = O[qi][dt];
      o *= inv;
      *(f32x4*)(op + dt * 16 + lq * 4) = o;
    }
  }
}

// ============ launcher ============
extern "C" void kernel_launch(void* const* d_in, const int* in_sizes, int n_in,
                              void* d_out, int out_size, void* d_ws, size_t ws_size,
                              hipStream_t stream) {
  const float* X    = (const float*)d_in[0];
  const float* mask = (const float*)d_in[1];
  const float* Wq   = (const float*)d_in[2];
  const float* bq   = (const float*)d_in[3];
  const float* Wk   = (const float*)d_in[4];
  const float* bk   = (const float*)d_in[5];
  const float* Wv   = (const float*)d_in[6];
  const float* bv   = (const float*)d_in[7];
  float* out = (float*)d_out;

  char* ws = (char*)d_ws;
  bf16_t* Xb = (bf16_t*)(ws);                        // 25165824 B
  bf16_t* Wb = (bf16_t*)(ws + 25165824);             //  3538944 B
  bf16_t* Qb = (bf16_t*)(ws + 28704768);             // 25165824 B
  bf16_t* Kb = (bf16_t*)(ws + 53870592);             // 25165824 B
  bf16_t* VT = (bf16_t*)(ws + 79036416);             // 25165824 B

  cvt_kernel<<<14016, 256, 0, stream>>>(X, Wq, Wk, Wv, Xb, Wb);
  qkv_gemm<<<2304, 256, 0, stream>>>(Xb, Wb, bq, bk, bv, Qb, Kb, VT);
  flash_kernel<<<768, 512, 0, stream>>>(Qb, Kb, VT, mask, out);
}

// Round 14
// 288.280 us; speedup vs baseline: 1.7968x; 1.0314x over previous
//
#include <hip/hip_runtime.h>

typedef __bf16 bf16_t;
typedef __bf16 bf16x8 __attribute__((ext_vector_type(8)));
typedef __bf16 bf16x4 __attribute__((ext_vector_type(4)));
typedef float  f32x4  __attribute__((ext_vector_type(4)));
typedef short  s16x4  __attribute__((ext_vector_type(4)));

#define DEV __device__ __forceinline__

// ---- constants ----
#define BB 8
#define SS 2048
#define HH 768
#define NHH 12
#define HD 64
#define NX (BB*SS*HH)      // 12582912
#define NW (HH*HH)         // 589824
#define NMASK (BB*SS)      // 16384

// async global->LDS, 16B per lane; LDS dest must be wave-uniform base + lane*16
DEV void gl_lds16(const void* g, void* s) {
  __builtin_amdgcn_global_load_lds(
      (__attribute__((address_space(1))) void*)(void*)g,
      (__attribute__((address_space(3))) void*)s, 16, 0, 0);
}

DEV int swz4(int r) { return (r ^ (r >> 2)) & 3; }   // 4-chunk (64B) rows

DEV f32x4 mfma32(bf16x8 a, bf16x8 b, f32x4 c) {
  return __builtin_amdgcn_mfma_f32_16x16x32_bf16(a, b, c, 0, 0, 0);
}

// ============ kernel 1: fp32 -> bf16 conversion + mask pre-scale ============
// Round-14: also converts mask -> mask*log2(e) (64 KB) so flash's inner loop
// loads marg directly (deletes 16 v_mul/kt/wave from flash's VALU stream).
__global__ __launch_bounds__(256) void cvt_kernel(
    const float* __restrict__ X, const float* __restrict__ Wq,
    const float* __restrict__ Wk, const float* __restrict__ Wv,
    const float* __restrict__ mask,
    bf16_t* __restrict__ Xb, bf16_t* __restrict__ Wb,
    float* __restrict__ maskE) {
  int idx = (blockIdx.x * 256 + threadIdx.x) * 4;
  if (idx < NX) {
    float4 v = *(const float4*)(X + idx);
    bf16x4 o;
    o[0] = (bf16_t)v.x; o[1] = (bf16_t)v.y; o[2] = (bf16_t)v.z; o[3] = (bf16_t)v.w;
    *(bf16x4*)(Xb + idx) = o;
  } else {
    int j = idx - NX;
    if (j < 3 * NW) {
      int w = j / NW;
      int jj = j - w * NW;
      const float* src = (w == 0 ? Wq : (w == 1 ? Wk : Wv)) + jj;
      float4 v = *(const float4*)src;
      bf16x4 o;
      o[0] = (bf16_t)v.x; o[1] = (bf16_t)v.y; o[2] = (bf16_t)v.z; o[3] = (bf16_t)v.w;
      *(bf16x4*)(Wb + j) = o;
    } else {
      int mi = j - 3 * NW;
      float4 v = *(const float4*)(mask + mi);
      const float L2E = 1.44269504f;
      float4 o = make_float4(v.x * L2E, v.y * L2E, v.z * L2E, v.w * L2E);
      *(float4*)(maskE + mi) = o;
    }
  }
}

// ============ kernel 2: fused QKV projection GEMM ============
// z=0 -> Q [b][h][s][d] PRE-SCALED by 0.125*log2(e), z=1 -> K
// z=2 -> V^T [b][h][d][s] with a PERMUTED kv order inside every 64-block:
//   stored = (i>>1)*32 + lq*8 + (i&1)*4 + r   for original sb = i*16+lq*4+r.
// Epilogue-through-LDS (r12, verified: total 326.6 -> 303.8): staging LDS is
// reused as the 128x128 output tile; writes swizzled ds_write_b64, readback
// 8x ds_read_b128 + 8x fully-coalesced 16B global stores.
// XCD-chunked swizzle (r8): swz = (id&7)*288 + id>>3.
__global__ __launch_bounds__(256) void qkv_gemm(
    const bf16_t* __restrict__ Xb, const bf16_t* __restrict__ Wb,
    const float* __restrict__ bq, const float* __restrict__ bk,
    const float* __restrict__ bv,
    bf16_t* __restrict__ Q, bf16_t* __restrict__ K, bf16_t* __restrict__ VT) {
  // [0:4096) A buf0 | [4096:8192) A buf1 | [8192:12288) B buf0 | [12288:16384) B buf1
  // (elems).  Reused whole as the 128x128 bf16 epilogue tile (32 KB).
  __shared__ alignas(16) bf16_t ldsAll[16384];

  const int t = threadIdx.x;
  const int w = t >> 6, l = t & 63, lr = l & 15, lq = l >> 4;
  const int wr = w >> 1, wc = w & 1;

  const int id = blockIdx.x;
  const int swz = (id & 7) * 288 + (id >> 3);       // XCD-chunked remap
  const int z = swz / 768;
  const int rem = swz - z * 768;
  const int m0 = (rem / 6) * 128, n0 = (rem % 6) * 128;

  const bf16_t* W = Wb + z * NW;
  const float* bias = (z == 0) ? bq : (z == 1) ? bk : bv;
  // Q carries the softmax scale 0.125 and the exp2 conversion log2(e):
  const float osc = (z == 0) ? 0.1803368801f : 1.0f;

  const int sl0 = t, sl1 = t + 256;
  const int ra0 = sl0 >> 2, qa0 = (sl0 & 3) ^ swz4(ra0);
  const int ra1 = sl1 >> 2, qa1 = (sl1 & 3) ^ swz4(ra1);
  const bf16_t* A0 = Xb + (m0 + ra0) * HH + qa0 * 8;
  const bf16_t* A1 = Xb + (m0 + ra1) * HH + qa1 * 8;
  const bf16_t* B0 = W + (n0 + ra0) * HH + qa0 * 8;
  const bf16_t* B1 = W + (n0 + ra1) * HH + qa1 * 8;

  f32x4 acc[4][4] = {};

  // offA: X-panel fragment offsets (m rows, wr); offB: W-panel (n rows, wc)
  int offA[4], offB[4];
#pragma unroll
  for (int i = 0; i < 4; ++i) {
    int Ra = wr * 64 + i * 16 + lr;
    offA[i] = (Ra * 4 + (lq ^ swz4(Ra))) * 8;
    int Rb = wc * 64 + i * 16 + lr;
    offB[i] = (Rb * 4 + (lq ^ swz4(Rb))) * 8;
  }

  // Operand selection: mfma(op0, op1): D row(lq,r) <- op0 rows, col(lr) <- op1.
  // z==2: op0 = X (row=m), op1 = W (col=n)  [tile quad along m=s, V^T fast axis]
  // z<2 : op0 = W (row=n), op1 = X (col=m)  [tile quad along n=d, Q/K fast axis]
  const bool zv = (z == 2);
  const bf16_t* LI = zv ? ldsAll : ldsAll + 8192;
  const bf16_t* LJ = zv ? ldsAll + 8192 : ldsAll;
  int offI[4], offJ[4];
#pragma unroll
  for (int i = 0; i < 4; ++i) {
    offI[i] = zv ? offA[i] : offB[i];
    offJ[i] = zv ? offB[i] : offA[i];
  }

  auto stage = [&](int buf, int kt) {
    int ko = kt * 32;
    bf16_t* LA = ldsAll + buf * 4096;
    bf16_t* LB = ldsAll + 8192 + buf * 4096;
    gl_lds16(A0 + ko, LA + sl0 * 8);
    gl_lds16(A1 + ko, LA + sl1 * 8);
    gl_lds16(B0 + ko, LB + sl0 * 8);
    gl_lds16(B1 + ko, LB + sl1 * 8);
  };

  auto compute = [&](const int buf) {
    bf16x8 fa[4], fb[4];
#pragma unroll
    for (int i = 0; i < 4; ++i) fa[i] = *(const bf16x8*)(LI + buf * 4096 + offI[i]);
#pragma unroll
    for (int j = 0; j < 4; ++j) fb[j] = *(const bf16x8*)(LJ + buf * 4096 + offJ[j]);
#pragma unroll
    for (int i = 0; i < 4; ++i)
#pragma unroll
      for (int j = 0; j < 4; ++j)
        acc[i][j] = __builtin_amdgcn_mfma_f32_16x16x32_bf16(fa[i], fb[j], acc[i][j], 0, 0, 0);
  };

  stage(0, 0);
  __syncthreads();     // tile0 drained
  stage(1, 1);         // in flight under compute(0)
  compute(0);
  for (int kt = 1; kt < 23; kt += 2) {
    __syncthreads();   // drains stage(buf1,kt); all waves done with buf0
    stage(0, kt + 1);
    compute(1);
    __syncthreads();   // drains stage(buf0,kt+1); all waves done with buf1
    stage(1, kt + 2);
    compute(0);
  }
  __syncthreads();     // drains stage(buf1,23)
  compute(1);

  // ======== epilogue through LDS ========
  __syncthreads();     // all waves done reading staging buffers
  char* T = (char*)ldsAll;   // 128 rows x 256 B (16 chunks of 16 B), XOR-swizzled

  if (zv) {
    // ---- tile [n=row][m_stored], quad along m (natural orientation) ----
#pragma unroll
    for (int j = 0; j < 4; ++j) {
      int row = wc * 64 + j * 16 + lr;                 // n_tile
      float bbias = bias[n0 + row];
#pragma unroll
      for (int i = 0; i < 4; ++i) {
        int chunkC = wr * 8 + (i >> 1) * 4 + lq;       // (m_stored quad)>>3
        int byteoff = row * 256 + ((chunkC ^ (row & 15)) * 16) + (i & 1) * 8;
        bf16x4 pk;
#pragma unroll
        for (int r = 0; r < 4; ++r) pk[r] = (bf16_t)(acc[i][j][r] + bbias);
        *(bf16x4*)(T + byteoff) = pk;
      }
    }
  } else {
    // ---- tile [m=row][n], quad along n (swapped orientation) ----
#pragma unroll
    for (int j = 0; j < 4; ++j) {
      int row = wr * 64 + j * 16 + lr;                 // m_tile
#pragma unroll
      for (int i = 0; i < 4; ++i) {
        int nq = wc * 64 + i * 16 + lq * 4;            // n quad base
        f32x4 bi = *(const f32x4*)(bias + n0 + nq);
        int chunkC = nq >> 3;
        int byteoff = row * 256 + ((chunkC ^ (row & 15)) * 16) + (lq & 1) * 8;
        bf16x4 pk;
#pragma unroll
        for (int r = 0; r < 4; ++r) pk[r] = (bf16_t)((acc[i][j][r] + bi[r]) * osc);
        *(bf16x4*)(T + byteoff) = pk;
      }
    }
  }
  __syncthreads();

  // ---- phase 2: 8x (ds_read_b128 + coalesced 16B global store) ----
  const int b = m0 >> 11, sbase = m0 & 2047;
  if (zv) {
#pragma unroll
    for (int it = 0; it < 8; ++it) {
      int flat = it * 256 + t;
      int row = flat >> 4, k = flat & 15;
      bf16x8 v = *(const bf16x8*)(T + row * 256 + ((k ^ (row & 15)) * 16));
      int n = n0 + row, h = n >> 6, d = n & 63;
      *(bf16x8*)(VT + ((size_t)(b * NHH + h) * HD + d) * SS + sbase + k * 8) = v;
    }
  } else {
    bf16_t* O = (z == 0) ? Q : K;
    const int h0 = n0 >> 6;
#pragma unroll
    for (int it = 0; it < 8; ++it) {
      int flat = it * 256 + t;
      int row = flat >> 4, k = flat & 15;
      bf16x8 v = *(const bf16x8*)(T + row * 256 + ((k ^ (row & 15)) * 16));
      *(bf16x8*)(O + ((size_t)(b * NHH + h0 + (k >> 3)) * SS + sbase + row) * HD + (k & 7) * 8) = v;
    }
  }
}

// ============ kernel 3: flash attention (QBLK=256, 512 threads) ============
// r13 verified: x32-only MFMA, permuted-V register-concat P, 0 bank
// conflicts, halved K/V staging (768 blocks), 131.3us.  Occupancy stayed 35%
// at 8 waves/block -> the ~26% all-idle is STRUCTURAL (per-kt barrier +
// serial QK->exp->PV chain), not residency.  r14: (a) marg loaded pre-scaled
// (mask*log2e from cvt) -- deletes 16 v_mul/kt/wave; (b) s_setprio(1) around
// the Lsum+PV MFMA cluster (T5: 3 independent blocks/CU = phase diversity).
// (512,4) = 128-VGPR cap, NO squeeze (r1/r9: forced caps below natural -> spill).
__global__ __launch_bounds__(512, 4) void flash_kernel(
    const bf16_t* __restrict__ Q, const bf16_t* __restrict__ K,
    const bf16_t* __restrict__ VT, const float* __restrict__ maskE,
    float* __restrict__ out) {
  // [buf][0] = K tile (64x64), [buf][1] = V^T tile (64x64).  32768 B total.
  __shared__ alignas(16) bf16_t ldsKV[2][2][64 * 64];

  const int t = threadIdx.x;
  const int w = t >> 6, l = t & 63, lr = l & 15, lq = l >> 4;
  const int rs7 = lr & 7;
  const int bh = blockIdx.x % 96, b = bh / NHH, h = bh - b * NHH;
  const int s0 = (blockIdx.x / 96) * 256;
  const bf16_t* Qb = Q + ((size_t)bh * SS + s0) * HD;
  const bf16_t* Kb = K + (size_t)bh * SS * HD;
  const bf16_t* Vb = VT + (size_t)bh * HD * SS;
  const float* mb = maskE + b * SS;

  // ---- stage Q (256x64 = 32 KB) into the WHOLE K/V region, xor swizzle ----
  bf16_t* qs = &ldsKV[0][0][0];
#pragma unroll
  for (int i = 0; i < 4; ++i) {
    int sl = t + i * 512;
    int r = sl >> 3, q = (sl & 7) ^ (r & 7);
    gl_lds16(Qb + r * HD + q * 8, qs + sl * 8);
  }
  __syncthreads();   // Q staged

  bf16x8 aq0[2], aq1[2];
#pragma unroll
  for (int qi = 0; qi < 2; ++qi) {
    int Rq = w * 32 + qi * 16 + lr;          // w in 0..7 -> rows 0..255
    aq0[qi] = *(const bf16x8*)(qs + (Rq * 8 + (lq ^ (Rq & 7))) * 8);
    aq1[qi] = *(const bf16x8*)(qs + (Rq * 8 + ((lq + 4) ^ (Rq & 7))) * 8);
  }
  __syncthreads();   // all waves hold Q in registers; region reusable for K/V

  const int cr = t >> 3, cq = (t & 7) ^ (cr & 7);   // 512 lanes = whole 8KB tile

  auto stage = [&](int buf, int kt) {
    gl_lds16(Kb + kt * 64 * HD + cr * HD + cq * 8, ldsKV[buf][0] + t * 8);
    gl_lds16(Vb + cr * SS + kt * 64 + cq * 8,      ldsKV[buf][1] + t * 8);
  };

  // ---- per-lane LDS byte bases (loop-invariant; reads = base + imm) ----
  // K: row Rk = j*16+lr, chunk lq / lq+4 (xor rs7), + j*2048
  const char* LB = (const char*)&ldsKV[0][0][0];
  const int kb0 = lr * 128 + ((lq ^ rs7) * 16);
  const int kb1 = lr * 128 + (((lq + 4) ^ rs7) * 16);
  // V (x32 A-frag): row d = dt*16+lr, stored-octet chunk gi*4+lq (xor rs7)
  int vg[2];
#pragma unroll
  for (int g = 0; g < 2; ++g) vg[g] = lr * 128 + (((g * 4 + lq) ^ rs7) * 16);

  f32x4 O[2][4] = {};
  f32x4 Lacc[2] = {};
  bf16x8 ones8;
#pragma unroll
  for (int r = 0; r < 8; ++r) ones8[r] = (bf16_t)1.0f;

  // BUFB: byte offset of the double-buffer half (0 or 16384) — literal at call sites.
  auto compute = [&](const int BUFB, int kt) {
    const char* Kbase = LB + BUFB;
    const char* Vbase = LB + BUFB + 8192;

#pragma unroll
    for (int gi = 0; gi < 2; ++gi) {
      bf16x8 pf[2];   // per qi: x32 B-frag octet = concat of quads j=2gi, 2gi+1
#pragma unroll
      for (int jj = 0; jj < 2; ++jj) {
        const int j = gi * 2 + jj;
        bf16x8 k0 = *(const bf16x8*)(Kbase + kb0 + j * 2048);
        bf16x8 k1 = *(const bf16x8*)(Kbase + kb1 + j * 2048);
        f32x4 marg = *(const f32x4*)(mb + kt * 64 + j * 16 + lq * 4);  // pre-scaled
#pragma unroll
        for (int qi = 0; qi < 2; ++qi) {
          f32x4 st = mfma32(k0, aq0[qi], marg);
          st = mfma32(k1, aq1[qi], st);
#pragma unroll
          for (int r = 0; r < 4; ++r)
            pf[qi][jj * 4 + r] = (bf16_t)__builtin_amdgcn_exp2f(st[r]);
        }
      }
      // ---- Lsum + PV MFMA cluster, wave priority boosted (T5) ----
      __builtin_amdgcn_s_setprio(1);
      Lacc[0] = mfma32(ones8, pf[0], Lacc[0]);
      Lacc[1] = mfma32(ones8, pf[1], Lacc[1]);
#pragma unroll
      for (int dt = 0; dt < 4; ++dt) {
        bf16x8 av = *(const bf16x8*)(Vbase + vg[gi] + dt * 2048);
        O[0][dt] = mfma32(av, pf[0], O[0][dt]);
        O[1][dt] = mfma32(av, pf[1], O[1][dt]);
      }
      __builtin_amdgcn_s_setprio(0);
    }
  };

  stage(0, 0);
  __syncthreads();   // tile0 drained
  stage(1, 1);       // in flight under compute(0)
  compute(0, 0);
  for (int kt = 1; kt < 31; kt += 2) {
    __syncthreads();               // drains stage of buf1(kt); all waves done with buf0
    stage(0, kt + 1);
    compute(16384, kt);
    __syncthreads();               // drains stage of buf0(kt+1); all done with buf1
    stage(1, kt + 2);
    compute(0, kt + 1);
  }
  __syncthreads();
  compute(16384, 31);

  // ---- epilogue: inv from MFMA row-sum (no shuffles) ----
#pragma unroll
  for (int qi = 0; qi < 2; ++qi) {
    float inv = 1.0f / Lacc[qi][0];
    int srow = s0 + w * 32 + qi * 16 + lr;
    float* op = out + ((size_t)b * SS + srow) * HH + h * HD;
#pragma unroll
    for (int dt = 0; dt < 4; ++dt) {
      f32x4 o = O[qi][dt];
      o *= inv;
      *(f32x4*)(op + dt * 16 + lq * 4) = o;
    }
  }
}

// ============ launcher ============
extern "C" void kernel_launch(void* const* d_in, const int* in_sizes, int n_in,
                              void* d_out, int out_size, void* d_ws, size_t ws_size,
                              hipStream_t stream) {
  const float* X    = (const float*)d_in[0];
  const float* mask = (const float*)d_in[1];
  const float* Wq   = (const float*)d_in[2];
  const float* bq   = (const float*)d_in[3];
  const float* Wk   = (const float*)d_in[4];
  const float* bk   = (const float*)d_in[5];
  const float* Wv   = (const float*)d_in[6];
  const float* bv   = (const float*)d_in[7];
  float* out = (float*)d_out;

  char* ws = (char*)d_ws;
  bf16_t* Xb = (bf16_t*)(ws);                        // 25165824 B
  bf16_t* Wb = (bf16_t*)(ws + 25165824);             //  3538944 B
  bf16_t* Qb = (bf16_t*)(ws + 28704768);             // 25165824 B
  bf16_t* Kb = (bf16_t*)(ws + 53870592);             // 25165824 B
  bf16_t* VT = (bf16_t*)(ws + 79036416);             // 25165824 B
  float* maskE = (float*)(ws + 104202240);           //    65536 B

  cvt_kernel<<<14032, 256, 0, stream>>>(X, Wq, Wk, Wv, mask, Xb, Wb, maskE);
  qkv_gemm<<<2304, 256, 0, stream>>>(Xb, Wb, bq, bk, bv, Qb, Kb, VT);
  flash_kernel<<<768, 512, 0, stream>>>(Qb, Kb, VT, maskE, out);
}